// Round 9
// baseline (114.759 us; speedup 1.0000x reference)
//
#include <hip/hip_runtime.h>

#define N_IN   128
#define LAYERS 6
#define N_H    320
#define DEG    32
#define N_OUT  18
#define N_TOTAL (N_IN + LAYERS * N_H)       // 2048
#define BB     8                            // batch elements per block
#define N_HID_UNITS (LAYERS * N_H)          // 1920
#define N_UNITS (N_HID_UNITS + N_OUT)       // 1938

typedef _Float16 half2_t __attribute__((ext_vector_type(2)));
typedef _Float16 half8_t __attribute__((ext_vector_type(8)));

#if __has_builtin(__builtin_amdgcn_fdot2)
#define FDOT2(a, b, c) __builtin_amdgcn_fdot2((a), (b), (c), false)
#else
__device__ __forceinline__ float fdot2_sw(half2_t a, half2_t b, float c) {
    return c + (float)a[0] * (float)b[0] + (float)a[1] * (float)b[1];
}
#define FDOT2(a, b, c) fdot2_sw((a), (b), (c))
#endif

__device__ __forceinline__ float fast_tanh(float x) {
    float e = __expf(2.0f * x);
    return 1.0f - 2.0f * __builtin_amdgcn_rcpf(e + 1.0f);
}

// ---------------------------------------------------------------------------
// pack_kernel v2: fused table + per-wave bank-group scheduling.
// A 16B LDS row r occupies bank group (r & 7). In the policy kernel, wave w =
// 64 consecutive units; at gather step p every lane issues one ds_read_b128.
// We reorder each lane's 32 taps so that at step p lane l targets group
// (p + (l&7)) & 7  — a Latin square: exactly 8 lanes/group per instruction
// (4 per 32-lane half), i.e. conflict-free when every lane can follow the
// target. Greedy fallback (fullest bucket) when the target bucket is empty.
// All scheduling state in LDS — NO dynamically-indexed private arrays
// (R4/R7 lesson: those go to scratch and cost 20+ us).
// fused layout per unit (32 dwords): [0..15] offset pairs, [16..31] f16 weight pairs.
// ---------------------------------------------------------------------------
__global__ __launch_bounds__(64) void pack_kernel(
    const int* __restrict__ hid_src, const float* __restrict__ hid_w,
    const int* __restrict__ out_src, const float* __restrict__ out_w,
    unsigned int* __restrict__ fused)
{
    __shared__ int           sIdx[64][32];   // 8 KB  raw indices
    __shared__ float         sW[64][32];     // 8 KB  raw weights
    __shared__ unsigned char sSrt[64][32];   // 2 KB  tap ids sorted by group
    __shared__ unsigned char sOrd[64][32];   // 2 KB  final schedule (tap ids)
    __shared__ unsigned char sPtr[64][8];    // bucket read cursor
    __shared__ unsigned char sEnd[64][8];    // bucket end
    __shared__ unsigned char sTmp[64][8];    // bucket write cursor / counts

    const int l = threadIdx.x;
    const int u = blockIdx.x * 64 + l;
    const bool valid = u < N_UNITS;

    const int*   src = hid_src;     // safe dummies for invalid lanes
    const float* w   = hid_w;
    if (valid) {
        if (u < N_HID_UNITS) { src = hid_src + u * DEG;                 w = hid_w + u * DEG; }
        else                 { src = out_src + (u - N_HID_UNITS) * DEG; w = out_w + (u - N_HID_UNITS) * DEG; }
    }
    for (int d = 0; d < DEG; ++d) {
        sIdx[l][d] = valid ? src[d] : d;
        sW[l][d]   = valid ? w[d]   : 0.f;
    }

    // counting sort by bank group (idx & 7)
    for (int g = 0; g < 8; ++g) sTmp[l][g] = 0;
    for (int d = 0; d < DEG; ++d) sTmp[l][sIdx[l][d] & 7]++;
    {
        int acc = 0;
        for (int g = 0; g < 8; ++g) {
            int c = sTmp[l][g];
            sPtr[l][g] = (unsigned char)acc;   // start (read cursor)
            sTmp[l][g] = (unsigned char)acc;   // write cursor
            acc += c;
            sEnd[l][g] = (unsigned char)acc;   // end
        }
    }
    for (int d = 0; d < DEG; ++d) {
        int g = sIdx[l][d] & 7;
        sSrt[l][sTmp[l][g]++] = (unsigned char)d;
    }

    // schedule: position p targets group (p + (l&7)) & 7; fallback = fullest bucket
    const int c0 = l & 7;
    for (int p = 0; p < DEG; ++p) {
        int g = (p + c0) & 7;
        if (sPtr[l][g] >= sEnd[l][g]) {
            int best = -1, bestn = -1;
            for (int gg = 0; gg < 8; ++gg) {
                int n = (int)sEnd[l][gg] - (int)sPtr[l][gg];
                if (n > bestn) { bestn = n; best = gg; }
            }
            g = best;
        }
        sOrd[l][p] = sSrt[l][sPtr[l][g]++];
    }

    if (!valid) return;
    unsigned int* dst = fused + u * 32;
    for (int q = 0; q < 16; ++q) {
        int d0 = sOrd[l][2 * q];
        int d1 = sOrd[l][2 * q + 1];
        unsigned o0 = (unsigned)sIdx[l][d0] << 4;   // byte offset into 16B rows
        unsigned o1 = (unsigned)sIdx[l][d1] << 4;
        dst[q] = o0 | (o1 << 16);
        half2_t wp;
        wp[0] = (_Float16)sW[l][d0];
        wp[1] = (_Float16)sW[l][d1];
        dst[16 + q] = __builtin_bit_cast(unsigned int, wp);
    }
}

// ---- gather-dot (unchanged from R8: 42.7 us, identical to R5 perf) --------
#define LOADP(OD, G0, G1) do {                                             \
    unsigned _o0 = (OD) & 0xffffu;                                         \
    unsigned _o1 = (OD) >> 16;                                             \
    G0 = *(const uint4*)(sA + _o0);                                        \
    G1 = *(const uint4*)(sA + _o1);                                        \
} while (0)

#define CONSUME(G0, G1, WD) do {                                           \
    half2_t _wp = __builtin_bit_cast(half2_t, (WD));                       \
    unsigned _p0 = __builtin_amdgcn_perm(G1.x, G0.x, 0x05040100u);         \
    unsigned _p1 = __builtin_amdgcn_perm(G1.x, G0.x, 0x07060302u);         \
    unsigned _p2 = __builtin_amdgcn_perm(G1.y, G0.y, 0x05040100u);         \
    unsigned _p3 = __builtin_amdgcn_perm(G1.y, G0.y, 0x07060302u);         \
    unsigned _p4 = __builtin_amdgcn_perm(G1.z, G0.z, 0x05040100u);         \
    unsigned _p5 = __builtin_amdgcn_perm(G1.z, G0.z, 0x07060302u);         \
    unsigned _p6 = __builtin_amdgcn_perm(G1.w, G0.w, 0x05040100u);         \
    unsigned _p7 = __builtin_amdgcn_perm(G1.w, G0.w, 0x07060302u);         \
    acc0 = FDOT2(__builtin_bit_cast(half2_t, _p0), _wp, acc0);             \
    acc1 = FDOT2(__builtin_bit_cast(half2_t, _p1), _wp, acc1);             \
    acc2 = FDOT2(__builtin_bit_cast(half2_t, _p2), _wp, acc2);             \
    acc3 = FDOT2(__builtin_bit_cast(half2_t, _p3), _wp, acc3);             \
    acc4 = FDOT2(__builtin_bit_cast(half2_t, _p4), _wp, acc4);             \
    acc5 = FDOT2(__builtin_bit_cast(half2_t, _p5), _wp, acc5);             \
    acc6 = FDOT2(__builtin_bit_cast(half2_t, _p6), _wp, acc6);             \
    acc7 = FDOT2(__builtin_bit_cast(half2_t, _p7), _wp, acc7);             \
} while (0)

#define GATHER_UNIT(BASE) do {                                             \
    const uint4* _t = ftab + (BASE);                                       \
    uint4 _fo0 = _t[0], _fo1 = _t[1], _fo2 = _t[2], _fo3 = _t[3];          \
    uint4 _fw0 = _t[4], _fw1 = _t[5], _fw2 = _t[6], _fw3 = _t[7];          \
    uint4 ga0, ga1, gb0, gb1;                                              \
    LOADP(_fo0.x, ga0, ga1);                                               \
    LOADP(_fo0.y, gb0, gb1); CONSUME(ga0, ga1, _fw0.x);                    \
    LOADP(_fo0.z, ga0, ga1); CONSUME(gb0, gb1, _fw0.y);                    \
    LOADP(_fo0.w, gb0, gb1); CONSUME(ga0, ga1, _fw0.z);                    \
    LOADP(_fo1.x, ga0, ga1); CONSUME(gb0, gb1, _fw0.w);                    \
    LOADP(_fo1.y, gb0, gb1); CONSUME(ga0, ga1, _fw1.x);                    \
    LOADP(_fo1.z, ga0, ga1); CONSUME(gb0, gb1, _fw1.y);                    \
    LOADP(_fo1.w, gb0, gb1); CONSUME(ga0, ga1, _fw1.z);                    \
    LOADP(_fo2.x, ga0, ga1); CONSUME(gb0, gb1, _fw1.w);                    \
    LOADP(_fo2.y, gb0, gb1); CONSUME(ga0, ga1, _fw2.x);                    \
    LOADP(_fo2.z, ga0, ga1); CONSUME(gb0, gb1, _fw2.y);                    \
    LOADP(_fo2.w, gb0, gb1); CONSUME(ga0, ga1, _fw2.z);                    \
    LOADP(_fo3.x, ga0, ga1); CONSUME(gb0, gb1, _fw2.w);                    \
    LOADP(_fo3.y, gb0, gb1); CONSUME(ga0, ga1, _fw3.x);                    \
    LOADP(_fo3.z, ga0, ga1); CONSUME(gb0, gb1, _fw3.y);                    \
    LOADP(_fo3.w, gb0, gb1); CONSUME(ga0, ga1, _fw3.z);                    \
    CONSUME(gb0, gb1, _fw3.w);                                             \
} while (0)

__global__ __launch_bounds__(N_H, 5) void policy_kernel(
    const float* __restrict__ obs,       // [B][N_IN]
    const uint4* __restrict__ ftab,      // [N_UNITS][8] fused offsets+weights
    const float* __restrict__ hid_b,     // [L][N_H]
    const float* __restrict__ out_b,     // [N_OUT]
    float*       __restrict__ out)       // [B][N_OUT]
{
    // acts row r = 8 x f16 (one per batch elem) = 16 B -> one ds_read_b128/gather
    __shared__ alignas(16) unsigned char sA[N_TOTAL * 16];   // 32 KB

    const int tid = threadIdx.x;
    const int b0  = blockIdx.x * BB;
    const int n   = tid;

    if (tid < N_IN) {
        half8_t hv;
        #pragma unroll
        for (int j = 0; j < BB; ++j) hv[j] = (_Float16)obs[(b0 + j) * N_IN + tid];
        *(half8_t*)(sA + tid * 16) = hv;
    }
    __syncthreads();

    for (int l = 0; l < LAYERS; ++l) {
        float acc0 = 0.f, acc1 = 0.f, acc2 = 0.f, acc3 = 0.f;
        float acc4 = 0.f, acc5 = 0.f, acc6 = 0.f, acc7 = 0.f;
        GATHER_UNIT((l * N_H + n) * 8);

        float bias = hid_b[l * N_H + n];
        half8_t hv;
        hv[0] = (_Float16)fast_tanh(acc0 + bias);
        hv[1] = (_Float16)fast_tanh(acc1 + bias);
        hv[2] = (_Float16)fast_tanh(acc2 + bias);
        hv[3] = (_Float16)fast_tanh(acc3 + bias);
        hv[4] = (_Float16)fast_tanh(acc4 + bias);
        hv[5] = (_Float16)fast_tanh(acc5 + bias);
        hv[6] = (_Float16)fast_tanh(acc6 + bias);
        hv[7] = (_Float16)fast_tanh(acc7 + bias);
        // this layer writes rows it never reads; one barrier per layer suffices
        *(half8_t*)(sA + (N_IN + l * N_H + n) * 16) = hv;
        __syncthreads();
    }

    if (n < N_OUT) {
        float acc0 = 0.f, acc1 = 0.f, acc2 = 0.f, acc3 = 0.f;
        float acc4 = 0.f, acc5 = 0.f, acc6 = 0.f, acc7 = 0.f;
        GATHER_UNIT((N_HID_UNITS + n) * 8);
        float bias = out_b[n];
        out[(b0 + 0) * N_OUT + n] = fast_tanh(acc0 + bias);
        out[(b0 + 1) * N_OUT + n] = fast_tanh(acc1 + bias);
        out[(b0 + 2) * N_OUT + n] = fast_tanh(acc2 + bias);
        out[(b0 + 3) * N_OUT + n] = fast_tanh(acc3 + bias);
        out[(b0 + 4) * N_OUT + n] = fast_tanh(acc4 + bias);
        out[(b0 + 5) * N_OUT + n] = fast_tanh(acc5 + bias);
        out[(b0 + 6) * N_OUT + n] = fast_tanh(acc6 + bias);
        out[(b0 + 7) * N_OUT + n] = fast_tanh(acc7 + bias);
    }
}

extern "C" void kernel_launch(void* const* d_in, const int* in_sizes, int n_in,
                              void* d_out, int out_size, void* d_ws, size_t ws_size,
                              hipStream_t stream) {
    const float* obs     = (const float*)d_in[0];
    const int*   hid_src = (const int*)  d_in[1];
    const float* hid_w   = (const float*)d_in[2];
    const float* hid_b   = (const float*)d_in[3];
    const int*   out_src = (const int*)  d_in[4];
    const float* out_w   = (const float*)d_in[5];
    const float* out_b   = (const float*)d_in[6];
    float* out = (float*)d_out;
    unsigned int* fused = (unsigned int*)d_ws;   // 1938*32*4 = 248 KB

    const int batch = in_sizes[0] / N_IN;   // 8192

    pack_kernel<<<(N_UNITS + 63) / 64, 64, 0, stream>>>(
        hid_src, hid_w, out_src, out_w, fused);
    policy_kernel<<<batch / BB, N_H, 0, stream>>>(
        obs, (const uint4*)fused, hid_b, out_b, out);
}

// Round 10
// 102.593 us; speedup vs baseline: 1.1186x; 1.1186x over previous
//
#include <hip/hip_runtime.h>

#define N_IN   128
#define LAYERS 6
#define N_H    320
#define DEG    32
#define N_OUT  18
#define N_TOTAL (N_IN + LAYERS * N_H)       // 2048
#define BB     8                            // batch elements per block
#define N_HID_UNITS (LAYERS * N_H)          // 1920
#define N_UNITS (N_HID_UNITS + N_OUT)       // 1938

typedef _Float16 half2_t __attribute__((ext_vector_type(2)));
typedef _Float16 half8_t __attribute__((ext_vector_type(8)));

#if __has_builtin(__builtin_amdgcn_fdot2)
#define FDOT2(a, b, c) __builtin_amdgcn_fdot2((a), (b), (c), false)
#else
__device__ __forceinline__ float fdot2_sw(half2_t a, half2_t b, float c) {
    return c + (float)a[0] * (float)b[0] + (float)a[1] * (float)b[1];
}
#define FDOT2(a, b, c) fdot2_sw((a), (b), (c))
#endif

__device__ __forceinline__ float fast_tanh(float x) {
    float e = __expf(2.0f * x);
    return 1.0f - 2.0f * __builtin_amdgcn_rcpf(e + 1.0f);
}

// fused table per unit (32 dwords): [0..15] = offset pairs (idx0*16 | idx1*16<<16),
//                                   [16..31] = weight half2 pairs.
// NOTE (R7/R9 evidence): bank-group tap scheduling cut SQ_LDS_BANK_CONFLICT up
// to -27% with ZERO time change — random wave64 ds_read_b128 costs ~26 cyc
// fixed (crossbar-phase-limited); conflict shaping is not on the critical
// path. So the pack stays the cheap unsorted version.
__global__ __launch_bounds__(64) void pack_kernel(
    const int* __restrict__ hid_src, const float* __restrict__ hid_w,
    const int* __restrict__ out_src, const float* __restrict__ out_w,
    unsigned int* __restrict__ fused)
{
    int u = blockIdx.x * 64 + threadIdx.x;
    if (u >= N_UNITS) return;
    const int*   src;
    const float* w;
    if (u < N_HID_UNITS) { src = hid_src + u * DEG;                 w = hid_w + u * DEG; }
    else                 { src = out_src + (u - N_HID_UNITS) * DEG; w = out_w + (u - N_HID_UNITS) * DEG; }
    unsigned int* dst = fused + u * 32;
    for (int q = 0; q < 16; ++q) {
        unsigned o0 = (unsigned)src[2 * q]     << 4;   // byte offset into 16B rows
        unsigned o1 = (unsigned)src[2 * q + 1] << 4;
        dst[q] = o0 | (o1 << 16);
        half2_t wp;
        wp[0] = (_Float16)w[2 * q];
        wp[1] = (_Float16)w[2 * q + 1];
        dst[16 + q] = __builtin_bit_cast(unsigned int, wp);
    }
}

// ---- gather-dot: one random ds_read_b128 serves 8 batch elems -------------
#define LOADP(OD, G0, G1) do {                                             \
    unsigned _o0 = (OD) & 0xffffu;                                         \
    unsigned _o1 = (OD) >> 16;                                             \
    G0 = *(const uint4*)(sA + _o0);                                        \
    G1 = *(const uint4*)(sA + _o1);                                        \
} while (0)

#define CONSUME(G0, G1, WD) do {                                           \
    half2_t _wp = __builtin_bit_cast(half2_t, (WD));                       \
    unsigned _p0 = __builtin_amdgcn_perm(G1.x, G0.x, 0x05040100u);         \
    unsigned _p1 = __builtin_amdgcn_perm(G1.x, G0.x, 0x07060302u);         \
    unsigned _p2 = __builtin_amdgcn_perm(G1.y, G0.y, 0x05040100u);         \
    unsigned _p3 = __builtin_amdgcn_perm(G1.y, G0.y, 0x07060302u);         \
    unsigned _p4 = __builtin_amdgcn_perm(G1.z, G0.z, 0x05040100u);         \
    unsigned _p5 = __builtin_amdgcn_perm(G1.z, G0.z, 0x07060302u);         \
    unsigned _p6 = __builtin_amdgcn_perm(G1.w, G0.w, 0x05040100u);         \
    unsigned _p7 = __builtin_amdgcn_perm(G1.w, G0.w, 0x07060302u);         \
    acc0 = FDOT2(__builtin_bit_cast(half2_t, _p0), _wp, acc0);             \
    acc1 = FDOT2(__builtin_bit_cast(half2_t, _p1), _wp, acc1);             \
    acc2 = FDOT2(__builtin_bit_cast(half2_t, _p2), _wp, acc2);             \
    acc3 = FDOT2(__builtin_bit_cast(half2_t, _p3), _wp, acc3);             \
    acc4 = FDOT2(__builtin_bit_cast(half2_t, _p4), _wp, acc4);             \
    acc5 = FDOT2(__builtin_bit_cast(half2_t, _p5), _wp, acc5);             \
    acc6 = FDOT2(__builtin_bit_cast(half2_t, _p6), _wp, acc6);             \
    acc7 = FDOT2(__builtin_bit_cast(half2_t, _p7), _wp, acc7);             \
} while (0)

// 16 tap-pairs, register double-buffered (neutral vs plain, kept from R8).
#define GATHER_UNIT(BASE) do {                                             \
    const uint4* _t = ftab + (BASE);                                       \
    uint4 _fo0 = _t[0], _fo1 = _t[1], _fo2 = _t[2], _fo3 = _t[3];          \
    uint4 _fw0 = _t[4], _fw1 = _t[5], _fw2 = _t[6], _fw3 = _t[7];          \
    uint4 ga0, ga1, gb0, gb1;                                              \
    LOADP(_fo0.x, ga0, ga1);                                               \
    LOADP(_fo0.y, gb0, gb1); CONSUME(ga0, ga1, _fw0.x);                    \
    LOADP(_fo0.z, ga0, ga1); CONSUME(gb0, gb1, _fw0.y);                    \
    LOADP(_fo0.w, gb0, gb1); CONSUME(ga0, ga1, _fw0.z);                    \
    LOADP(_fo1.x, ga0, ga1); CONSUME(gb0, gb1, _fw0.w);                    \
    LOADP(_fo1.y, gb0, gb1); CONSUME(ga0, ga1, _fw1.x);                    \
    LOADP(_fo1.z, ga0, ga1); CONSUME(gb0, gb1, _fw1.y);                    \
    LOADP(_fo1.w, gb0, gb1); CONSUME(ga0, ga1, _fw1.z);                    \
    LOADP(_fo2.x, ga0, ga1); CONSUME(gb0, gb1, _fw1.w);                    \
    LOADP(_fo2.y, gb0, gb1); CONSUME(ga0, ga1, _fw2.x);                    \
    LOADP(_fo2.z, ga0, ga1); CONSUME(gb0, gb1, _fw2.y);                    \
    LOADP(_fo2.w, gb0, gb1); CONSUME(ga0, ga1, _fw2.z);                    \
    LOADP(_fo3.x, ga0, ga1); CONSUME(gb0, gb1, _fw2.w);                    \
    LOADP(_fo3.y, gb0, gb1); CONSUME(ga0, ga1, _fw3.x);                    \
    LOADP(_fo3.z, ga0, ga1); CONSUME(gb0, gb1, _fw3.y);                    \
    LOADP(_fo3.w, gb0, gb1); CONSUME(ga0, ga1, _fw3.z);                    \
    CONSUME(gb0, gb1, _fw3.w);                                             \
} while (0)

__global__ __launch_bounds__(N_H, 5) void policy_kernel(
    const float* __restrict__ obs,       // [B][N_IN]
    const uint4* __restrict__ ftab,      // [N_UNITS][8] fused offsets+weights
    const float* __restrict__ hid_b,     // [L][N_H]
    const float* __restrict__ out_b,     // [N_OUT]
    float*       __restrict__ out)       // [B][N_OUT]
{
    // acts row r = 8 x f16 (one per batch elem) = 16 B -> one ds_read_b128/gather
    __shared__ alignas(16) unsigned char sA[N_TOTAL * 16];   // 32 KB -> 5 blocks/CU

    const int tid = threadIdx.x;
    const int b0  = blockIdx.x * BB;
    const int n   = tid;

    if (tid < N_IN) {
        half8_t hv;
        #pragma unroll
        for (int j = 0; j < BB; ++j) hv[j] = (_Float16)obs[(b0 + j) * N_IN + tid];
        *(half8_t*)(sA + tid * 16) = hv;
    }
    __syncthreads();

    for (int l = 0; l < LAYERS; ++l) {
        float acc0 = 0.f, acc1 = 0.f, acc2 = 0.f, acc3 = 0.f;
        float acc4 = 0.f, acc5 = 0.f, acc6 = 0.f, acc7 = 0.f;
        GATHER_UNIT((l * N_H + n) * 8);

        float bias = hid_b[l * N_H + n];
        half8_t hv;
        hv[0] = (_Float16)fast_tanh(acc0 + bias);
        hv[1] = (_Float16)fast_tanh(acc1 + bias);
        hv[2] = (_Float16)fast_tanh(acc2 + bias);
        hv[3] = (_Float16)fast_tanh(acc3 + bias);
        hv[4] = (_Float16)fast_tanh(acc4 + bias);
        hv[5] = (_Float16)fast_tanh(acc5 + bias);
        hv[6] = (_Float16)fast_tanh(acc6 + bias);
        hv[7] = (_Float16)fast_tanh(acc7 + bias);
        // this layer writes rows it never reads; one barrier per layer suffices
        *(half8_t*)(sA + (N_IN + l * N_H + n) * 16) = hv;
        __syncthreads();
    }

    if (n < N_OUT) {
        float acc0 = 0.f, acc1 = 0.f, acc2 = 0.f, acc3 = 0.f;
        float acc4 = 0.f, acc5 = 0.f, acc6 = 0.f, acc7 = 0.f;
        GATHER_UNIT((N_HID_UNITS + n) * 8);
        float bias = out_b[n];
        out[(b0 + 0) * N_OUT + n] = fast_tanh(acc0 + bias);
        out[(b0 + 1) * N_OUT + n] = fast_tanh(acc1 + bias);
        out[(b0 + 2) * N_OUT + n] = fast_tanh(acc2 + bias);
        out[(b0 + 3) * N_OUT + n] = fast_tanh(acc3 + bias);
        out[(b0 + 4) * N_OUT + n] = fast_tanh(acc4 + bias);
        out[(b0 + 5) * N_OUT + n] = fast_tanh(acc5 + bias);
        out[(b0 + 6) * N_OUT + n] = fast_tanh(acc6 + bias);
        out[(b0 + 7) * N_OUT + n] = fast_tanh(acc7 + bias);
    }
}

extern "C" void kernel_launch(void* const* d_in, const int* in_sizes, int n_in,
                              void* d_out, int out_size, void* d_ws, size_t ws_size,
                              hipStream_t stream) {
    const float* obs     = (const float*)d_in[0];
    const int*   hid_src = (const int*)  d_in[1];
    const float* hid_w   = (const float*)d_in[2];
    const float* hid_b   = (const float*)d_in[3];
    const int*   out_src = (const int*)  d_in[4];
    const float* out_w   = (const float*)d_in[5];
    const float* out_b   = (const float*)d_in[6];
    float* out = (float*)d_out;
    unsigned int* fused = (unsigned int*)d_ws;   // 1938*32*4 = 248 KB

    const int batch = in_sizes[0] / N_IN;   // 8192

    pack_kernel<<<(N_UNITS + 63) / 64, 64, 0, stream>>>(
        hid_src, hid_w, out_src, out_w, fused);
    policy_kernel<<<batch / BB, N_H, 0, stream>>>(
        obs, (const uint4*)fused, hid_b, out_b, out);
}